// Round 1
// baseline (526.973 us; speedup 1.0000x reference)
//
#include <hip/hip_runtime.h>
#include <hip/hip_bf16.h>

#define CIN 512
#define OQK 64
#define NBATCH 4
#define NTOK 4096

typedef float f32x4 __attribute__((ext_vector_type(4)));
typedef _Float16 f16x8 __attribute__((ext_vector_type(8)));
typedef short s16x8 __attribute__((ext_vector_type(8)));
typedef unsigned short u16;

__device__ inline u16 f2bf(float f) {
    unsigned u = __float_as_uint(f);
    u += 0x7fffu + ((u >> 16) & 1u);
    return (u16)(u >> 16);
}
__device__ inline u16 f2h_bits(float f) {
    _Float16 h = (_Float16)f;
    return __builtin_bit_cast(unsigned short, h);
}

// ---------------- Q/K projection: Q[b][n][o], K[b][m][o] (f16) ----------------
// D[n][o] = sum_c x^T[n][c] * W[o][c]   (A = x^T gathered, B = W contiguous)
__global__ __launch_bounds__(256, 2) void proj_qk(
    const float* __restrict__ x, const float* __restrict__ Wq, const float* __restrict__ bq,
    const float* __restrict__ Wk, const float* __restrict__ bk,
    u16* __restrict__ Qh, u16* __restrict__ Kh)
{
    const int nb = blockIdx.x;   // 64 blocks of 64 tokens
    const int b  = blockIdx.y;   // 4
    const int tid = threadIdx.x;
    const int w = tid >> 6, l = tid & 63;
    const int lr = l & 15, lg = l >> 4;

    const int n = nb * 64 + w * 16 + lr;                 // A-frag row (token)
    const float* xs = x + (size_t)b * CIN * NTOK;        // x_s[b]
    const float* xt = x + (size_t)(b + NBATCH) * CIN * NTOK; // x_t[b]

    f32x4 accQ[4] = {};
    f32x4 accK[4] = {};

    for (int t = 0; t < 16; ++t) {
        const int c0 = t * 32 + lg * 8;
        f16x8 As, At;
        #pragma unroll
        for (int j = 0; j < 8; ++j) {
            As[j] = (_Float16)xs[(size_t)(c0 + j) * NTOK + n];
            At[j] = (_Float16)xt[(size_t)(c0 + j) * NTOK + n];
        }
        #pragma unroll
        for (int of = 0; of < 4; ++of) {
            const int o = of * 16 + lr;
            const float* wq = Wq + (size_t)o * CIN + c0;
            const float* wk = Wk + (size_t)o * CIN + c0;
            f16x8 Bq, Bk;
            #pragma unroll
            for (int j = 0; j < 8; ++j) { Bq[j] = (_Float16)wq[j]; Bk[j] = (_Float16)wk[j]; }
            accQ[of] = __builtin_amdgcn_mfma_f32_16x16x32_f16(As, Bq, accQ[of], 0, 0, 0);
            accK[of] = __builtin_amdgcn_mfma_f32_16x16x32_f16(At, Bk, accK[of], 0, 0, 0);
        }
    }
    #pragma unroll
    for (int of = 0; of < 4; ++of) {
        const int o = of * 16 + lr;
        const float bqv = bq[o], bkv = bk[o];
        #pragma unroll
        for (int r = 0; r < 4; ++r) {
            const int nn = nb * 64 + w * 16 + lg * 4 + r;
            Qh[((size_t)b * NTOK + nn) * OQK + o] = f2h_bits(accQ[of][r] + bqv);
            Kh[((size_t)b * NTOK + nn) * OQK + o] = f2h_bits(accK[of][r] + bkv);
        }
    }
}

// ---------------- V projection: V[b][c][m] (bf16) ----------------
// D[c][m] = sum_cin Wv[c][cin] * x_t[cin][m]  (A = Wv contiguous, B = x_t^T gathered)
__global__ __launch_bounds__(512, 2) void proj_v(
    const float* __restrict__ x, const float* __restrict__ Wv, const float* __restrict__ bv,
    u16* __restrict__ Vb)
{
    const int mb = blockIdx.x;   // 64 blocks of 64 tokens
    const int b  = blockIdx.y;
    const int tid = threadIdx.x;
    const int w = tid >> 6, l = tid & 63;
    const int lr = l & 15, lg = l >> 4;

    const float* xt = x + (size_t)(b + NBATCH) * CIN * NTOK;

    f32x4 acc[4][4] = {};   // [cf][fm]
    for (int t = 0; t < 16; ++t) {
        const int c0 = t * 32 + lg * 8;
        f16x8 Bf[4];
        #pragma unroll
        for (int fm = 0; fm < 4; ++fm) {
            const int mm = mb * 64 + fm * 16 + lr;
            #pragma unroll
            for (int j = 0; j < 8; ++j) Bf[fm][j] = (_Float16)xt[(size_t)(c0 + j) * NTOK + mm];
        }
        #pragma unroll
        for (int cf = 0; cf < 4; ++cf) {
            const int c = w * 64 + cf * 16 + lr;
            const float* wv = Wv + (size_t)c * CIN + c0;
            f16x8 A;
            #pragma unroll
            for (int j = 0; j < 8; ++j) A[j] = (_Float16)wv[j];
            #pragma unroll
            for (int fm = 0; fm < 4; ++fm)
                acc[cf][fm] = __builtin_amdgcn_mfma_f32_16x16x32_f16(A, Bf[fm], acc[cf][fm], 0, 0, 0);
        }
    }
    #pragma unroll
    for (int cf = 0; cf < 4; ++cf) {
        #pragma unroll
        for (int fm = 0; fm < 4; ++fm) {
            #pragma unroll
            for (int r = 0; r < 4; ++r) {
                const int c  = w * 64 + cf * 16 + lg * 4 + r;
                const int mm = mb * 64 + fm * 16 + lr;
                Vb[((size_t)b * CIN + c) * NTOK + mm] = f2bf(acc[cf][fm][r] + bv[c]);
            }
        }
    }
}

// ---------------- fused attention + residual ----------------
// one WG per (b, 64-row q block); 8 waves.
// S-role: wave w -> fn = w>>1 (16 rows), fm pair = (w&1)*2 + {0,1}
// PV-role: wave w -> rg = w>>2 (32 rows), cg = w&3 (128 channels)
__global__ __launch_bounds__(512, 2) void attn(
    const float* __restrict__ x, const u16* __restrict__ Qh, const u16* __restrict__ Kh,
    const u16* __restrict__ Vb, float* __restrict__ out)
{
    __shared__ u16 Pt[64][72];
    __shared__ float den_lds[64];

    const int nb = blockIdx.x, b = blockIdx.y;
    const int tid = threadIdx.x;
    const int w = tid >> 6, l = tid & 63;
    const int lr = l & 15, lg = l >> 4;
    const int fn = w >> 1, fmb = (w & 1) * 2;
    const int rg = w >> 2, cg = w & 3;

    if (tid < 64) den_lds[tid] = 0.f;

    // hoisted Q A-fragments (loop-invariant)
    f16x8 Aq0, Aq1;
    {
        const u16* qp = Qh + ((size_t)b * NTOK + nb * 64 + fn * 16 + lr) * OQK + lg * 8;
        Aq0 = *reinterpret_cast<const f16x8*>(qp);
        Aq1 = *reinterpret_cast<const f16x8*>(qp + 32);
    }

    f32x4 acc[2][8] = {};
    float den[4] = {0.f, 0.f, 0.f, 0.f};
    const u16* Kbase = Kh + (size_t)b * NTOK * OQK;
    const u16* Vbase = Vb + (size_t)b * CIN * NTOK;

    for (int mt = 0; mt < 64; ++mt) {
        const int m0 = mt * 64;
        // ---- S = Q K^T, P = exp(S), P -> LDS ----
        #pragma unroll
        for (int i = 0; i < 2; ++i) {
            const int fm = fmb + i;
            const u16* kp = Kbase + (size_t)(m0 + fm * 16 + lr) * OQK + lg * 8;
            f16x8 Bk0 = *reinterpret_cast<const f16x8*>(kp);
            f16x8 Bk1 = *reinterpret_cast<const f16x8*>(kp + 32);
            f32x4 s = {};
            s = __builtin_amdgcn_mfma_f32_16x16x32_f16(Aq0, Bk0, s, 0, 0, 0);
            s = __builtin_amdgcn_mfma_f32_16x16x32_f16(Aq1, Bk1, s, 0, 0, 0);
            #pragma unroll
            for (int r = 0; r < 4; ++r) {
                // no max-subtraction: |S| <~ 50, exp fits fp32/bf16 comfortably
                float p = __expf(s[r]);
                den[r] += p;
                Pt[fn * 16 + lg * 4 + r][fm * 16 + lr] = f2bf(p);
            }
        }
        __syncthreads();
        // ---- load P A-fragments ----
        s16x8 Pa[2][2];
        #pragma unroll
        for (int a = 0; a < 2; ++a) {
            #pragma unroll
            for (int kk = 0; kk < 2; ++kk)
                Pa[a][kk] = *reinterpret_cast<const s16x8*>(&Pt[rg * 32 + a * 16 + lr][kk * 32 + lg * 8]);
        }
        __syncthreads();
        // ---- PV: acc[n][c] += P * V^T ----
        #pragma unroll
        for (int fc = 0; fc < 8; ++fc) {
            const u16* vp = Vbase + (size_t)(cg * 128 + fc * 16 + lr) * NTOK + m0 + lg * 8;
            s16x8 Bv0 = *reinterpret_cast<const s16x8*>(vp);
            s16x8 Bv1 = *reinterpret_cast<const s16x8*>(vp + 32);
            acc[0][fc] = __builtin_amdgcn_mfma_f32_16x16x32_bf16(Pa[0][0], Bv0, acc[0][fc], 0, 0, 0);
            acc[1][fc] = __builtin_amdgcn_mfma_f32_16x16x32_bf16(Pa[1][0], Bv0, acc[1][fc], 0, 0, 0);
            acc[0][fc] = __builtin_amdgcn_mfma_f32_16x16x32_bf16(Pa[0][1], Bv1, acc[0][fc], 0, 0, 0);
            acc[1][fc] = __builtin_amdgcn_mfma_f32_16x16x32_bf16(Pa[1][1], Bv1, acc[1][fc], 0, 0, 0);
        }
    }

    // ---- denominator: reduce across the 16 lanes sharing rows, combine fm-halves in LDS ----
    #pragma unroll
    for (int r = 0; r < 4; ++r) {
        float d = den[r];
        d += __shfl_xor(d, 1);
        d += __shfl_xor(d, 2);
        d += __shfl_xor(d, 4);
        d += __shfl_xor(d, 8);
        den[r] = d;
    }
    if (lr == 0) {
        #pragma unroll
        for (int r = 0; r < 4; ++r)
            atomicAdd(&den_lds[fn * 16 + lg * 4 + r], den[r]);
    }
    __syncthreads();

    // ---- epilogue: out = x_t + (acc / den), float4 stores ----
    float inv[2][4];
    #pragma unroll
    for (int a = 0; a < 2; ++a) {
        #pragma unroll
        for (int r = 0; r < 4; ++r)
            inv[a][r] = 1.0f / den_lds[rg * 32 + a * 16 + lg * 4 + r];
    }
    const float* xtp = x + (size_t)(b + NBATCH) * CIN * NTOK;
    float* op = out + (size_t)(b + NBATCH) * CIN * NTOK;
    #pragma unroll
    for (int a = 0; a < 2; ++a) {
        #pragma unroll
        for (int fc = 0; fc < 8; ++fc) {
            const int c = cg * 128 + fc * 16 + lr;
            const size_t base = (size_t)c * NTOK + nb * 64 + rg * 32 + a * 16 + lg * 4;
            f32x4 xv = *reinterpret_cast<const f32x4*>(xtp + base);
            f32x4 o;
            #pragma unroll
            for (int r = 0; r < 4; ++r) o[r] = xv[r] + acc[a][fc][r] * inv[a][r];
            *reinterpret_cast<f32x4*>(op + base) = o;
        }
    }
}

extern "C" void kernel_launch(void* const* d_in, const int* in_sizes, int n_in,
                              void* d_out, int out_size, void* d_ws, size_t ws_size,
                              hipStream_t stream)
{
    (void)in_sizes; (void)n_in; (void)out_size; (void)ws_size;
    const float* x  = (const float*)d_in[0];
    const float* Wq = (const float*)d_in[1];
    const float* bq = (const float*)d_in[2];
    const float* Wk = (const float*)d_in[3];
    const float* bk = (const float*)d_in[4];
    const float* Wv = (const float*)d_in[5];
    const float* bv = (const float*)d_in[6];
    float* out = (float*)d_out;

    u16* Qh = (u16*)d_ws;                                   // 4*4096*64 f16
    u16* Kh = Qh + (size_t)NBATCH * NTOK * OQK;             // 4*4096*64 f16
    u16* Vb = Kh + (size_t)NBATCH * NTOK * OQK;             // 4*512*4096 bf16

    // first half of output: x_s unchanged
    hipMemcpyAsync(d_out, x, (size_t)NBATCH * CIN * NTOK * sizeof(float),
                   hipMemcpyDeviceToDevice, stream);

    proj_qk<<<dim3(64, NBATCH), 256, 0, stream>>>(x, Wq, bq, Wk, bk, Qh, Kh);
    proj_v <<<dim3(64, NBATCH), 512, 0, stream>>>(x, Wv, bv, Vb);
    attn   <<<dim3(64, NBATCH), 512, 0, stream>>>(x, Qh, Kh, Vb, out);
}

// Round 2
// 480.022 us; speedup vs baseline: 1.0978x; 1.0978x over previous
//
#include <hip/hip_runtime.h>
#include <hip/hip_bf16.h>

#define CIN 512
#define OQK 64
#define NBATCH 4
#define NTOK 4096

typedef float f32x4 __attribute__((ext_vector_type(4)));
typedef _Float16 f16x8 __attribute__((ext_vector_type(8)));
typedef short s16x8 __attribute__((ext_vector_type(8)));
typedef unsigned short u16;

__device__ inline u16 f2bf(float f) {
    unsigned u = __float_as_uint(f);
    u += 0x7fffu + ((u >> 16) & 1u);
    return (u16)(u >> 16);
}
__device__ inline u16 f2h_bits(float f) {
    _Float16 h = (_Float16)f;
    return __builtin_bit_cast(unsigned short, h);
}
__device__ inline f16x8 cvt8(const f32x4 a, const f32x4 b) {
    f16x8 r;
    #pragma unroll
    for (int j = 0; j < 4; ++j) { r[j] = (_Float16)a[j]; r[j + 4] = (_Float16)b[j]; }
    return r;
}

// ---------------- Q/K projection: Q[b][n][o], K[b][m][o] (f16) ----------------
// 32 tokens per block, 2 waves; grid (128, NBATCH) = 512 WGs (2/CU)
__global__ __launch_bounds__(128, 4) void proj_qk(
    const float* __restrict__ x, const float* __restrict__ Wq, const float* __restrict__ bq,
    const float* __restrict__ Wk, const float* __restrict__ bk,
    u16* __restrict__ Qh, u16* __restrict__ Kh)
{
    const int nb = blockIdx.x;   // 128 blocks of 32 tokens
    const int b  = blockIdx.y;   // 4
    const int tid = threadIdx.x;
    const int w = tid >> 6, l = tid & 63;
    const int lr = l & 15, lg = l >> 4;

    const int n = nb * 32 + w * 16 + lr;                 // A-frag row (token)
    const float* xs = x + (size_t)b * CIN * NTOK;
    const float* xt = x + (size_t)(b + NBATCH) * CIN * NTOK;

    f32x4 accQ[4] = {};
    f32x4 accK[4] = {};

    for (int t = 0; t < 16; ++t) {
        const int c0 = t * 32 + lg * 8;
        f16x8 As, At;
        #pragma unroll
        for (int j = 0; j < 8; ++j) {
            As[j] = (_Float16)xs[(size_t)(c0 + j) * NTOK + n];
            At[j] = (_Float16)xt[(size_t)(c0 + j) * NTOK + n];
        }
        #pragma unroll
        for (int of = 0; of < 4; ++of) {
            const int o = of * 16 + lr;
            const float* wq = Wq + (size_t)o * CIN + c0;
            const float* wk = Wk + (size_t)o * CIN + c0;
            f16x8 Bq = cvt8(*(const f32x4*)wq, *(const f32x4*)(wq + 4));
            f16x8 Bk = cvt8(*(const f32x4*)wk, *(const f32x4*)(wk + 4));
            accQ[of] = __builtin_amdgcn_mfma_f32_16x16x32_f16(As, Bq, accQ[of], 0, 0, 0);
            accK[of] = __builtin_amdgcn_mfma_f32_16x16x32_f16(At, Bk, accK[of], 0, 0, 0);
        }
    }
    #pragma unroll
    for (int of = 0; of < 4; ++of) {
        const int o = of * 16 + lr;
        const float bqv = bq[o], bkv = bk[o];
        #pragma unroll
        for (int r = 0; r < 4; ++r) {
            const int nn = nb * 32 + w * 16 + lg * 4 + r;
            Qh[((size_t)b * NTOK + nn) * OQK + o] = f2h_bits(accQ[of][r] + bqv);
            Kh[((size_t)b * NTOK + nn) * OQK + o] = f2h_bits(accK[of][r] + bkv);
        }
    }
}

// ---------------- V projection: V[b][c][m] (bf16) ----------------
// 32 tokens per block, 4 waves (each 128 channels); grid (128, NBATCH) = 512 WGs
__global__ __launch_bounds__(256, 4) void proj_v(
    const float* __restrict__ x, const float* __restrict__ Wv, const float* __restrict__ bv,
    u16* __restrict__ Vb)
{
    const int mb = blockIdx.x;   // 128 blocks of 32 tokens
    const int b  = blockIdx.y;
    const int tid = threadIdx.x;
    const int w = tid >> 6, l = tid & 63;
    const int lr = l & 15, lg = l >> 4;

    const float* xt = x + (size_t)(b + NBATCH) * CIN * NTOK;

    f32x4 acc[8][2] = {};   // [cf][fm]
    for (int t = 0; t < 16; ++t) {
        const int c0 = t * 32 + lg * 8;
        f16x8 Bf[2];
        #pragma unroll
        for (int fm = 0; fm < 2; ++fm) {
            const int mm = mb * 32 + fm * 16 + lr;
            #pragma unroll
            for (int j = 0; j < 8; ++j) Bf[fm][j] = (_Float16)xt[(size_t)(c0 + j) * NTOK + mm];
        }
        #pragma unroll
        for (int cf = 0; cf < 8; ++cf) {
            const int c = w * 128 + cf * 16 + lr;
            const float* wv = Wv + (size_t)c * CIN + c0;
            f16x8 A = cvt8(*(const f32x4*)wv, *(const f32x4*)(wv + 4));
            #pragma unroll
            for (int fm = 0; fm < 2; ++fm)
                acc[cf][fm] = __builtin_amdgcn_mfma_f32_16x16x32_f16(A, Bf[fm], acc[cf][fm], 0, 0, 0);
        }
    }
    #pragma unroll
    for (int cf = 0; cf < 8; ++cf) {
        #pragma unroll
        for (int fm = 0; fm < 2; ++fm) {
            #pragma unroll
            for (int r = 0; r < 4; ++r) {
                const int c  = w * 128 + cf * 16 + lg * 4 + r;
                const int mm = mb * 32 + fm * 16 + lr;
                Vb[((size_t)b * CIN + c) * NTOK + mm] = f2bf(acc[cf][fm][r] + bv[c]);
            }
        }
    }
}

// ---------------- fused attention + residual (software-pipelined) ----------------
// one WG per (b, 64-row q block); 8 waves; 1 barrier per m-tile.
__global__ __launch_bounds__(512, 2) void attn(
    const float* __restrict__ x, const u16* __restrict__ Qh, const u16* __restrict__ Kh,
    const u16* __restrict__ Vb, float* __restrict__ out)
{
    __shared__ u16 Pt[2][64][72];
    __shared__ float den_lds[64];

    const int nb = blockIdx.x, b = blockIdx.y;
    const int tid = threadIdx.x;
    const int w = tid >> 6, l = tid & 63;
    const int lr = l & 15, lg = l >> 4;
    const int fn = w >> 1, fmb = (w & 1) * 2;
    const int rg = w >> 2, cg = w & 3;

    if (tid < 64) den_lds[tid] = 0.f;

    // hoisted Q A-fragments (loop-invariant)
    f16x8 Aq0, Aq1;
    {
        const u16* qp = Qh + ((size_t)b * NTOK + nb * 64 + fn * 16 + lr) * OQK + lg * 8;
        Aq0 = *reinterpret_cast<const f16x8*>(qp);
        Aq1 = *reinterpret_cast<const f16x8*>(qp + 32);
    }

    f32x4 acc[2][8] = {};
    float den[4] = {0.f, 0.f, 0.f, 0.f};
    const u16* Kbase = Kh + (size_t)b * NTOK * OQK;
    const u16* Vbase = Vb + (size_t)b * CIN * NTOK;

    f16x8 Kf[2][2][2];   // [reg-buf][fm-idx][k-half]

    auto loadK = [&](int mtile, int buf) {
        #pragma unroll
        for (int i = 0; i < 2; ++i) {
            const u16* kp = Kbase + (size_t)(mtile * 64 + (fmb + i) * 16 + lr) * OQK + lg * 8;
            Kf[buf][i][0] = *reinterpret_cast<const f16x8*>(kp);
            Kf[buf][i][1] = *reinterpret_cast<const f16x8*>(kp + 32);
        }
    };
    // compute S for a tile using Kf[buf], write P -> Pt[pbuf], accumulate den
    auto sphase = [&](int buf, int pbuf) {
        #pragma unroll
        for (int i = 0; i < 2; ++i) {
            f32x4 s = {};
            s = __builtin_amdgcn_mfma_f32_16x16x32_f16(Aq0, Kf[buf][i][0], s, 0, 0, 0);
            s = __builtin_amdgcn_mfma_f32_16x16x32_f16(Aq1, Kf[buf][i][1], s, 0, 0, 0);
            #pragma unroll
            for (int r = 0; r < 4; ++r) {
                float p = __expf(s[r]);   // |S| small enough; no max subtraction needed
                den[r] += p;
                Pt[pbuf][fn * 16 + lg * 4 + r][(fmb + i) * 16 + lr] = f2bf(p);
            }
        }
    };

    // prologue: S(0) -> Pt[0]; K(1) in flight
    loadK(0, 0);
    sphase(0, 0);
    loadK(1, 1);

    #pragma unroll 2
    for (int mt = 0; mt < 64; ++mt) {
        const int cur = mt & 1;
        __syncthreads();                       // Pt[cur] (tile mt) now visible

        // issue V loads for tile mt (consumed after the S-phase below)
        const int m0 = mt * 64;
        s16x8 Vc[8][2];
        #pragma unroll
        for (int fc = 0; fc < 8; ++fc) {
            const u16* vp = Vbase + (size_t)(cg * 128 + fc * 16 + lr) * NTOK + m0 + lg * 8;
            Vc[fc][0] = *reinterpret_cast<const s16x8*>(vp);
            Vc[fc][1] = *reinterpret_cast<const s16x8*>(vp + 32);
        }

        // read P fragments for tile mt
        s16x8 Pa[2][2];
        #pragma unroll
        for (int a = 0; a < 2; ++a) {
            #pragma unroll
            for (int kk = 0; kk < 2; ++kk)
                Pa[a][kk] = *reinterpret_cast<const s16x8*>(&Pt[cur][rg * 32 + a * 16 + lr][kk * 32 + lg * 8]);
        }

        // S-phase for tile mt+1 (K was prefetched 2 tiles ahead); issue K(mt+2)
        if (mt < 63) {
            sphase(cur ^ 1, cur ^ 1);
            if (mt < 62) loadK(mt + 2, cur);
        }

        // PV for tile mt
        __builtin_amdgcn_s_setprio(1);
        #pragma unroll
        for (int fc = 0; fc < 8; ++fc) {
            acc[0][fc] = __builtin_amdgcn_mfma_f32_16x16x32_bf16(Pa[0][0], Vc[fc][0], acc[0][fc], 0, 0, 0);
            acc[1][fc] = __builtin_amdgcn_mfma_f32_16x16x32_bf16(Pa[1][0], Vc[fc][0], acc[1][fc], 0, 0, 0);
            acc[0][fc] = __builtin_amdgcn_mfma_f32_16x16x32_bf16(Pa[0][1], Vc[fc][1], acc[0][fc], 0, 0, 0);
            acc[1][fc] = __builtin_amdgcn_mfma_f32_16x16x32_bf16(Pa[1][1], Vc[fc][1], acc[1][fc], 0, 0, 0);
        }
        __builtin_amdgcn_s_setprio(0);
    }

    // ---- denominator: reduce across the 16 lanes sharing rows, combine fm-halves ----
    #pragma unroll
    for (int r = 0; r < 4; ++r) {
        float d = den[r];
        d += __shfl_xor(d, 1);
        d += __shfl_xor(d, 2);
        d += __shfl_xor(d, 4);
        d += __shfl_xor(d, 8);
        den[r] = d;
    }
    if (lr == 0) {
        #pragma unroll
        for (int r = 0; r < 4; ++r)
            atomicAdd(&den_lds[fn * 16 + lg * 4 + r], den[r]);
    }
    __syncthreads();

    // ---- epilogue: out = x_t + (acc / den), float4 loads/stores ----
    float inv[2][4];
    #pragma unroll
    for (int a = 0; a < 2; ++a) {
        #pragma unroll
        for (int r = 0; r < 4; ++r)
            inv[a][r] = 1.0f / den_lds[rg * 32 + a * 16 + lg * 4 + r];
    }
    const float* xtp = x + (size_t)(b + NBATCH) * CIN * NTOK;
    float* op = out + (size_t)(b + NBATCH) * CIN * NTOK;
    #pragma unroll
    for (int a = 0; a < 2; ++a) {
        #pragma unroll
        for (int fc = 0; fc < 8; ++fc) {
            const int c = cg * 128 + fc * 16 + lr;
            const size_t base = (size_t)c * NTOK + nb * 64 + rg * 32 + a * 16 + lg * 4;
            f32x4 xv = *reinterpret_cast<const f32x4*>(xtp + base);
            f32x4 o;
            #pragma unroll
            for (int r = 0; r < 4; ++r) o[r] = xv[r] + acc[a][fc][r] * inv[a][r];
            *reinterpret_cast<f32x4*>(op + base) = o;
        }
    }
}

extern "C" void kernel_launch(void* const* d_in, const int* in_sizes, int n_in,
                              void* d_out, int out_size, void* d_ws, size_t ws_size,
                              hipStream_t stream)
{
    (void)in_sizes; (void)n_in; (void)out_size; (void)ws_size;
    const float* x  = (const float*)d_in[0];
    const float* Wq = (const float*)d_in[1];
    const float* bq = (const float*)d_in[2];
    const float* Wk = (const float*)d_in[3];
    const float* bk = (const float*)d_in[4];
    const float* Wv = (const float*)d_in[5];
    const float* bv = (const float*)d_in[6];
    float* out = (float*)d_out;

    u16* Qh = (u16*)d_ws;                                   // 4*4096*64 f16
    u16* Kh = Qh + (size_t)NBATCH * NTOK * OQK;             // 4*4096*64 f16
    u16* Vb = Kh + (size_t)NBATCH * NTOK * OQK;             // 4*512*4096 bf16

    // first half of output: x_s unchanged
    hipMemcpyAsync(d_out, x, (size_t)NBATCH * CIN * NTOK * sizeof(float),
                   hipMemcpyDeviceToDevice, stream);

    proj_qk<<<dim3(128, NBATCH), 128, 0, stream>>>(x, Wq, bq, Wk, bk, Qh, Kh);
    proj_v <<<dim3(128, NBATCH), 256, 0, stream>>>(x, Wv, bv, Vb);
    attn   <<<dim3(64, NBATCH), 512, 0, stream>>>(x, Qh, Kh, Vb, out);
}

// Round 3
// 307.594 us; speedup vs baseline: 1.7132x; 1.5606x over previous
//
#include <hip/hip_runtime.h>
#include <hip/hip_bf16.h>

#define CIN 512
#define OQK 64
#define NBATCH 4
#define NTOK 4096

typedef float f32x4 __attribute__((ext_vector_type(4)));
typedef _Float16 f16x8 __attribute__((ext_vector_type(8)));
typedef short s16x8 __attribute__((ext_vector_type(8)));
typedef unsigned short u16;

__device__ inline u16 f2bf(float f) {
    unsigned u = __float_as_uint(f);
    u += 0x7fffu + ((u >> 16) & 1u);
    return (u16)(u >> 16);
}
__device__ inline u16 f2h_bits(float f) {
    _Float16 h = (_Float16)f;
    return __builtin_bit_cast(unsigned short, h);
}
__device__ inline f16x8 cvt8(const f32x4 a, const f32x4 b) {
    f16x8 r;
    #pragma unroll
    for (int j = 0; j < 4; ++j) { r[j] = (_Float16)a[j]; r[j + 4] = (_Float16)b[j]; }
    return r;
}

// ---------------- Q/K projection: Q[b][n][o], K[b][m][o] (f16) ----------------
// 32 tokens/block, 4 waves: waves 0-1 compute Q (token halves), waves 2-3 compute K.
__global__ __launch_bounds__(256, 4) void proj_qk(
    const float* __restrict__ x, const float* __restrict__ Wq, const float* __restrict__ bq,
    const float* __restrict__ Wk, const float* __restrict__ bk,
    u16* __restrict__ Qh, u16* __restrict__ Kh)
{
    const int nb = blockIdx.x;   // 128 blocks of 32 tokens
    const int b  = blockIdx.y;   // 4
    const int tid = threadIdx.x;
    const int w = tid >> 6, l = tid & 63;
    const int lr = l & 15, lg = l >> 4;
    const int qk = w >> 1, half = w & 1;

    const int n = nb * 32 + half * 16 + lr;
    const float* xsrc = x + (size_t)(b + (qk ? NBATCH : 0)) * CIN * NTOK;
    const float* W    = qk ? Wk : Wq;
    const float* bias = qk ? bk : bq;
    u16* outp         = qk ? Kh : Qh;

    f32x4 acc[4] = {};
    for (int t = 0; t < 16; ++t) {
        const int c0 = t * 32 + lg * 8;
        f16x8 A;
        #pragma unroll
        for (int j = 0; j < 8; ++j) A[j] = (_Float16)xsrc[(size_t)(c0 + j) * NTOK + n];
        #pragma unroll
        for (int of = 0; of < 4; ++of) {
            const float* wp = W + (size_t)(of * 16 + lr) * CIN + c0;
            f16x8 B = cvt8(*(const f32x4*)wp, *(const f32x4*)(wp + 4));
            acc[of] = __builtin_amdgcn_mfma_f32_16x16x32_f16(A, B, acc[of], 0, 0, 0);
        }
    }
    #pragma unroll
    for (int of = 0; of < 4; ++of) {
        const int o = of * 16 + lr;
        const float bv_ = bias[o];
        #pragma unroll
        for (int r = 0; r < 4; ++r) {
            const int nn = nb * 32 + half * 16 + lg * 4 + r;
            outp[((size_t)b * NTOK + nn) * OQK + o] = f2h_bits(acc[of][r] + bv_);
        }
    }
}

// ---------------- V projection: V[b][c][m] (bf16) ----------------
__global__ __launch_bounds__(256, 4) void proj_v(
    const float* __restrict__ x, const float* __restrict__ Wv, const float* __restrict__ bv,
    u16* __restrict__ Vb)
{
    const int mb = blockIdx.x;   // 128 blocks of 32 tokens
    const int b  = blockIdx.y;
    const int tid = threadIdx.x;
    const int w = tid >> 6, l = tid & 63;
    const int lr = l & 15, lg = l >> 4;

    const float* xt = x + (size_t)(b + NBATCH) * CIN * NTOK;

    f32x4 acc[8][2] = {};   // [cf][fm]
    for (int t = 0; t < 16; ++t) {
        const int c0 = t * 32 + lg * 8;
        f16x8 Bf[2];
        #pragma unroll
        for (int fm = 0; fm < 2; ++fm) {
            const int mm = mb * 32 + fm * 16 + lr;
            #pragma unroll
            for (int j = 0; j < 8; ++j) Bf[fm][j] = (_Float16)xt[(size_t)(c0 + j) * NTOK + mm];
        }
        #pragma unroll
        for (int cf = 0; cf < 8; ++cf) {
            const int c = w * 128 + cf * 16 + lr;
            const float* wv = Wv + (size_t)c * CIN + c0;
            f16x8 A = cvt8(*(const f32x4*)wv, *(const f32x4*)(wv + 4));
            #pragma unroll
            for (int fm = 0; fm < 2; ++fm)
                acc[cf][fm] = __builtin_amdgcn_mfma_f32_16x16x32_f16(A, Bf[fm], acc[cf][fm], 0, 0, 0);
        }
    }
    #pragma unroll
    for (int cf = 0; cf < 8; ++cf) {
        #pragma unroll
        for (int fm = 0; fm < 2; ++fm) {
            #pragma unroll
            for (int r = 0; r < 4; ++r) {
                const int c  = w * 128 + cf * 16 + lg * 4 + r;
                const int mm = mb * 32 + fm * 16 + lr;
                Vb[((size_t)b * CIN + c) * NTOK + mm] = f2bf(acc[cf][fm][r] + bv[c]);
            }
        }
    }
}

// ---------------- fused attention + residual ----------------
// Grid: 256 blocks 1D, XCD-pinned: batch b owns XCDs {2b, 2b+1} so V[b]/K[b]
// stay L2-resident and all 32 co-XCD WGs share the streaming V window.
// PV decomposition: wave w owns channels [w*64, w*64+64), ALL 64 q-rows
// (no duplicate V loads within the WG).
__global__ __launch_bounds__(512, 2) void attn(
    const float* __restrict__ x, const u16* __restrict__ Qh, const u16* __restrict__ Kh,
    const u16* __restrict__ Vb, float* __restrict__ out)
{
    __shared__ u16 Pt[2][64][72];
    __shared__ float den_lds[64];

    const int g = blockIdx.x;
    const int xcd = g & 7;
    const int b = xcd >> 1;                       // batch -> XCD pair
    const int nb = ((g >> 3) << 1) | (xcd & 1);   // q-block within batch

    const int tid = threadIdx.x;
    const int w = tid >> 6, l = tid & 63;
    const int lr = l & 15, lg = l >> 4;
    const int fn = w >> 1, fmb = (w & 1) * 2;     // S-phase role
    const int cb = w * 64;                        // PV role: channel base

    if (tid < 64) den_lds[tid] = 0.f;

    // hoisted Q A-fragments
    f16x8 Aq0, Aq1;
    {
        const u16* qp = Qh + ((size_t)b * NTOK + nb * 64 + fn * 16 + lr) * OQK + lg * 8;
        Aq0 = *reinterpret_cast<const f16x8*>(qp);
        Aq1 = *reinterpret_cast<const f16x8*>(qp + 32);
    }

    f32x4 acc[4][4] = {};                         // [row-frag a][chan-frag cf]
    float den[4] = {0.f, 0.f, 0.f, 0.f};
    const u16* Kbase = Kh + (size_t)b * NTOK * OQK;
    const u16* Vbase = Vb + (size_t)b * CIN * NTOK;

    f16x8 Kf[2][2][2];    // [buf][fm-idx][k-half]
    s16x8 Vc[2][4][2];    // [buf][cf][kk]

    auto loadK = [&](int mtile, int buf) {
        #pragma unroll
        for (int i = 0; i < 2; ++i) {
            const u16* kp = Kbase + (size_t)(mtile * 64 + (fmb + i) * 16 + lr) * OQK + lg * 8;
            Kf[buf][i][0] = *reinterpret_cast<const f16x8*>(kp);
            Kf[buf][i][1] = *reinterpret_cast<const f16x8*>(kp + 32);
        }
    };
    auto loadV = [&](int mtile, int buf) {
        #pragma unroll
        for (int cf = 0; cf < 4; ++cf) {
            const u16* vp = Vbase + (size_t)(cb + cf * 16 + lr) * NTOK + mtile * 64 + lg * 8;
            Vc[buf][cf][0] = *reinterpret_cast<const s16x8*>(vp);
            Vc[buf][cf][1] = *reinterpret_cast<const s16x8*>(vp + 32);
        }
    };
    auto sphase = [&](int buf, int pbuf) {
        #pragma unroll
        for (int i = 0; i < 2; ++i) {
            f32x4 s = {};
            s = __builtin_amdgcn_mfma_f32_16x16x32_f16(Aq0, Kf[buf][i][0], s, 0, 0, 0);
            s = __builtin_amdgcn_mfma_f32_16x16x32_f16(Aq1, Kf[buf][i][1], s, 0, 0, 0);
            #pragma unroll
            for (int r = 0; r < 4; ++r) {
                float p = __expf(s[r]);   // |S| bounded; no max subtraction needed
                den[r] += p;
                Pt[pbuf][fn * 16 + lg * 4 + r][(fmb + i) * 16 + lr] = f2bf(p);
            }
        }
    };

    // prologue: tile 0 S-phase -> Pt[0]; V(0), K(1) prefetched
    loadK(0, 0);
    loadV(0, 0);
    sphase(0, 0);
    loadK(1, 1);

    #pragma unroll 2
    for (int mt = 0; mt < 64; ++mt) {
        const int cur = mt & 1;
        __syncthreads();                           // Pt[cur] visible; Vc[cur] in flight->done

        // prefetch V for tile mt+1 (consumed next iter; latency covered by S+PV)
        if (mt < 63) loadV(mt + 1, cur ^ 1);

        // P fragments for tile mt
        s16x8 Pa[4][2];
        #pragma unroll
        for (int a = 0; a < 4; ++a) {
            #pragma unroll
            for (int kk = 0; kk < 2; ++kk)
                Pa[a][kk] = *reinterpret_cast<const s16x8*>(&Pt[cur][a * 16 + lr][kk * 32 + lg * 8]);
        }

        // S-phase for tile mt+1; issue K(mt+2)
        if (mt < 63) {
            sphase(cur ^ 1, cur ^ 1);
            if (mt < 62) loadK(mt + 2, cur);
        }

        // PV for tile mt
        __builtin_amdgcn_s_setprio(1);
        #pragma unroll
        for (int cf = 0; cf < 4; ++cf) {
            #pragma unroll
            for (int a = 0; a < 4; ++a)
                acc[a][cf] = __builtin_amdgcn_mfma_f32_16x16x32_bf16(Pa[a][0], Vc[cur][cf][0], acc[a][cf], 0, 0, 0);
            #pragma unroll
            for (int a = 0; a < 4; ++a)
                acc[a][cf] = __builtin_amdgcn_mfma_f32_16x16x32_bf16(Pa[a][1], Vc[cur][cf][1], acc[a][cf], 0, 0, 0);
        }
        __builtin_amdgcn_s_setprio(0);
    }

    // ---- denominator reduce ----
    #pragma unroll
    for (int r = 0; r < 4; ++r) {
        float d = den[r];
        d += __shfl_xor(d, 1);
        d += __shfl_xor(d, 2);
        d += __shfl_xor(d, 4);
        d += __shfl_xor(d, 8);
        den[r] = d;
    }
    if (lr == 0) {
        #pragma unroll
        for (int r = 0; r < 4; ++r)
            atomicAdd(&den_lds[fn * 16 + lg * 4 + r], den[r]);
    }
    __syncthreads();

    // ---- epilogue: out = x_t + acc/den ----
    float inv[4][4];
    #pragma unroll
    for (int a = 0; a < 4; ++a) {
        #pragma unroll
        for (int r = 0; r < 4; ++r)
            inv[a][r] = 1.0f / den_lds[a * 16 + lg * 4 + r];
    }
    const float* xtp = x + (size_t)(b + NBATCH) * CIN * NTOK;
    float* op = out + (size_t)(b + NBATCH) * CIN * NTOK;
    #pragma unroll
    for (int a = 0; a < 4; ++a) {
        #pragma unroll
        for (int cf = 0; cf < 4; ++cf) {
            const int c = cb + cf * 16 + lr;
            const size_t base = (size_t)c * NTOK + nb * 64 + a * 16 + lg * 4;
            f32x4 xv = *reinterpret_cast<const f32x4*>(xtp + base);
            f32x4 o;
            #pragma unroll
            for (int r = 0; r < 4; ++r) o[r] = xv[r] + acc[a][cf][r] * inv[a][r];
            *reinterpret_cast<f32x4*>(op + base) = o;
        }
    }
}

extern "C" void kernel_launch(void* const* d_in, const int* in_sizes, int n_in,
                              void* d_out, int out_size, void* d_ws, size_t ws_size,
                              hipStream_t stream)
{
    (void)in_sizes; (void)n_in; (void)out_size; (void)ws_size;
    const float* x  = (const float*)d_in[0];
    const float* Wq = (const float*)d_in[1];
    const float* bq = (const float*)d_in[2];
    const float* Wk = (const float*)d_in[3];
    const float* bk = (const float*)d_in[4];
    const float* Wv = (const float*)d_in[5];
    const float* bv = (const float*)d_in[6];
    float* out = (float*)d_out;

    u16* Qh = (u16*)d_ws;                                   // 4*4096*64 f16
    u16* Kh = Qh + (size_t)NBATCH * NTOK * OQK;             // 4*4096*64 f16
    u16* Vb = Kh + (size_t)NBATCH * NTOK * OQK;             // 4*512*4096 bf16

    // first half of output: x_s unchanged
    hipMemcpyAsync(d_out, x, (size_t)NBATCH * CIN * NTOK * sizeof(float),
                   hipMemcpyDeviceToDevice, stream);

    proj_qk<<<dim3(128, NBATCH), 256, 0, stream>>>(x, Wq, bq, Wk, bk, Qh, Kh);
    proj_v <<<dim3(128, NBATCH), 256, 0, stream>>>(x, Wv, bv, Vb);
    attn   <<<256, 512, 0, stream>>>(x, Qh, Kh, Vb, out);
}

// Round 4
// 302.819 us; speedup vs baseline: 1.7402x; 1.0158x over previous
//
#include <hip/hip_runtime.h>
#include <hip/hip_bf16.h>

#define CIN 512
#define OQK 64
#define NBATCH 4
#define NTOK 4096

typedef float f32x4 __attribute__((ext_vector_type(4)));
typedef _Float16 f16x8 __attribute__((ext_vector_type(8)));
typedef short s16x8 __attribute__((ext_vector_type(8)));
typedef unsigned short u16;

__device__ inline u16 f2bf(float f) {
    unsigned u = __float_as_uint(f);
    u += 0x7fffu + ((u >> 16) & 1u);
    return (u16)(u >> 16);
}
__device__ inline u16 f2h_bits(float f) {
    _Float16 h = (_Float16)f;
    return __builtin_bit_cast(unsigned short, h);
}
__device__ inline f16x8 cvt8(const f32x4 a, const f32x4 b) {
    f16x8 r;
    #pragma unroll
    for (int j = 0; j < 4; ++j) { r[j] = (_Float16)a[j]; r[j + 4] = (_Float16)b[j]; }
    return r;
}

// ---------------- Q/K projection + fused x_s copy-out ----------------
// 32 tokens/block, 4 waves: waves 0-1 compute Q (and write x_s -> out), waves 2-3 compute K.
__global__ __launch_bounds__(256, 4) void proj_qk(
    const float* __restrict__ x, const float* __restrict__ Wq, const float* __restrict__ bq,
    const float* __restrict__ Wk, const float* __restrict__ bk,
    u16* __restrict__ Qh, u16* __restrict__ Kh, float* __restrict__ out)
{
    const int nb = blockIdx.x;   // 128 blocks of 32 tokens
    const int b  = blockIdx.y;   // 4
    const int tid = threadIdx.x;
    const int w = tid >> 6, l = tid & 63;
    const int lr = l & 15, lg = l >> 4;
    const int qk = w >> 1, half = w & 1;

    const int n = nb * 32 + half * 16 + lr;
    const float* xsrc = x + (size_t)(b + (qk ? NBATCH : 0)) * CIN * NTOK;
    const float* W    = qk ? Wk : Wq;
    const float* bias = qk ? bk : bq;
    u16* outp         = qk ? Kh : Qh;
    float* os         = out + (size_t)b * CIN * NTOK;   // x_s passthrough (Q-waves only)

    f32x4 acc[4] = {};
    for (int t = 0; t < 16; ++t) {
        const int c0 = t * 32 + lg * 8;
        f16x8 A;
        float av[8];
        #pragma unroll
        for (int j = 0; j < 8; ++j) {
            av[j] = xsrc[(size_t)(c0 + j) * NTOK + n];
            A[j] = (_Float16)av[j];
        }
        if (qk == 0) {
            #pragma unroll
            for (int j = 0; j < 8; ++j) os[(size_t)(c0 + j) * NTOK + n] = av[j];
        }
        #pragma unroll
        for (int of = 0; of < 4; ++of) {
            const float* wp = W + (size_t)(of * 16 + lr) * CIN + c0;
            f16x8 B = cvt8(*(const f32x4*)wp, *(const f32x4*)(wp + 4));
            acc[of] = __builtin_amdgcn_mfma_f32_16x16x32_f16(A, B, acc[of], 0, 0, 0);
        }
    }
    #pragma unroll
    for (int of = 0; of < 4; ++of) {
        const int o = of * 16 + lr;
        const float bv_ = bias[o];
        #pragma unroll
        for (int r = 0; r < 4; ++r) {
            const int nn = nb * 32 + half * 16 + lg * 4 + r;
            outp[((size_t)b * NTOK + nn) * OQK + o] = f2h_bits(acc[of][r] + bv_);
        }
    }
}

// ---------------- V projection: V[b][c][m] (bf16) ----------------
__global__ __launch_bounds__(256, 4) void proj_v(
    const float* __restrict__ x, const float* __restrict__ Wv, const float* __restrict__ bv,
    u16* __restrict__ Vb)
{
    const int mb = blockIdx.x;   // 128 blocks of 32 tokens
    const int b  = blockIdx.y;
    const int tid = threadIdx.x;
    const int w = tid >> 6, l = tid & 63;
    const int lr = l & 15, lg = l >> 4;

    const float* xt = x + (size_t)(b + NBATCH) * CIN * NTOK;

    f32x4 acc[8][2] = {};   // [cf][fm]
    for (int t = 0; t < 16; ++t) {
        const int c0 = t * 32 + lg * 8;
        f16x8 Bf[2];
        #pragma unroll
        for (int fm = 0; fm < 2; ++fm) {
            const int mm = mb * 32 + fm * 16 + lr;
            #pragma unroll
            for (int j = 0; j < 8; ++j) Bf[fm][j] = (_Float16)xt[(size_t)(c0 + j) * NTOK + mm];
        }
        #pragma unroll
        for (int cf = 0; cf < 8; ++cf) {
            const int c = w * 128 + cf * 16 + lr;
            const float* wv = Wv + (size_t)c * CIN + c0;
            f16x8 A = cvt8(*(const f32x4*)wv, *(const f32x4*)(wv + 4));
            #pragma unroll
            for (int fm = 0; fm < 2; ++fm)
                acc[cf][fm] = __builtin_amdgcn_mfma_f32_16x16x32_f16(A, Bf[fm], acc[cf][fm], 0, 0, 0);
        }
    }
    #pragma unroll
    for (int cf = 0; cf < 8; ++cf) {
        #pragma unroll
        for (int fm = 0; fm < 2; ++fm) {
            #pragma unroll
            for (int r = 0; r < 4; ++r) {
                const int c  = w * 128 + cf * 16 + lg * 4 + r;
                const int mm = mb * 32 + fm * 16 + lr;
                Vb[((size_t)b * CIN + c) * NTOK + mm] = f2bf(acc[cf][fm][r] + bv[c]);
            }
        }
    }
}

// ---------------- fused attention + residual ----------------
// Grid: 256 blocks 1D, XCD-pinned (batch b -> XCDs {2b,2b+1}).
// Static-indexed double buffers (no scratch); raw barrier (lgkmcnt only) so
// global prefetches stay in flight across barriers; XOR-swizzled P tile.

#define LOADK(mtile, KF)                                                        \
  { _Pragma("unroll")                                                           \
    for (int i_ = 0; i_ < 2; ++i_) {                                            \
      const u16* kp = Kbase + (size_t)((mtile) * 64 + (fmb + i_) * 16 + lr) * OQK + lg * 8; \
      KF[i_][0] = *reinterpret_cast<const f16x8*>(kp);                          \
      KF[i_][1] = *reinterpret_cast<const f16x8*>(kp + 32);                     \
    } }

#define LOADV(mtile, VC)                                                        \
  { _Pragma("unroll")                                                           \
    for (int cf_ = 0; cf_ < 4; ++cf_) {                                         \
      const u16* vp = Vbase + (size_t)(cb + cf_ * 16 + lr) * NTOK + (mtile) * 64 + lg * 8; \
      VC[cf_][0] = *reinterpret_cast<const s16x8*>(vp);                         \
      VC[cf_][1] = *reinterpret_cast<const s16x8*>(vp + 32);                    \
    } }

#define SPHASE(KF, PBUF)                                                        \
  { _Pragma("unroll")                                                           \
    for (int i_ = 0; i_ < 2; ++i_) {                                            \
      f32x4 s_ = {};                                                            \
      s_ = __builtin_amdgcn_mfma_f32_16x16x32_f16(Aq0, KF[i_][0], s_, 0, 0, 0); \
      s_ = __builtin_amdgcn_mfma_f32_16x16x32_f16(Aq1, KF[i_][1], s_, 0, 0, 0); \
      _Pragma("unroll")                                                         \
      for (int r_ = 0; r_ < 4; ++r_) {                                          \
        float p_ = __expf(s_[r_]);                                              \
        den[r_] += p_;                                                          \
        const int row_ = fn * 16 + lg * 4 + r_;                                 \
        const int col_ = (fmb + i_) * 16 + lr;                                  \
        Pt[(PBUF) * 4096 + row_ * 64 + (col_ ^ ((row_ & 7) << 3))] = f2bf(p_);  \
      } } }

#define BODY(CUR, VCC, VCN, KFN, KFC, mt)                                       \
  {                                                                             \
    asm volatile("s_waitcnt lgkmcnt(0)" ::: "memory");                          \
    __builtin_amdgcn_s_barrier();                                               \
    if ((mt) < 63) LOADV((mt) + 1, VCN);                                        \
    s16x8 Pa[4][2];                                                             \
    _Pragma("unroll")                                                           \
    for (int a_ = 0; a_ < 4; ++a_) {                                            \
      const int row_ = a_ * 16 + lr;                                            \
      const int sw_ = (row_ & 7) << 3;                                          \
      Pa[a_][0] = *(const s16x8*)&Pt[(CUR) * 4096 + row_ * 64 + ((lg * 8) ^ sw_)];        \
      Pa[a_][1] = *(const s16x8*)&Pt[(CUR) * 4096 + row_ * 64 + ((32 + lg * 8) ^ sw_)];   \
    }                                                                           \
    if ((mt) < 63) {                                                            \
      SPHASE(KFN, (CUR) ^ 1);                                                   \
      if ((mt) < 62) LOADK((mt) + 2, KFC);                                      \
    }                                                                           \
    __builtin_amdgcn_s_setprio(1);                                              \
    _Pragma("unroll")                                                           \
    for (int cf_ = 0; cf_ < 4; ++cf_) {                                         \
      _Pragma("unroll")                                                         \
      for (int a_ = 0; a_ < 4; ++a_)                                            \
        acc[a_][cf_] = __builtin_amdgcn_mfma_f32_16x16x32_bf16(Pa[a_][0], VCC[cf_][0], acc[a_][cf_], 0, 0, 0); \
      _Pragma("unroll")                                                         \
      for (int a_ = 0; a_ < 4; ++a_)                                            \
        acc[a_][cf_] = __builtin_amdgcn_mfma_f32_16x16x32_bf16(Pa[a_][1], VCC[cf_][1], acc[a_][cf_], 0, 0, 0); \
    }                                                                           \
    __builtin_amdgcn_s_setprio(0);                                              \
  }

__global__ __launch_bounds__(512, 2) void attn(
    const float* __restrict__ x, const u16* __restrict__ Qh, const u16* __restrict__ Kh,
    const u16* __restrict__ Vb, float* __restrict__ out)
{
    __shared__ u16 Pt[2 * 4096];
    __shared__ float den_lds[64];

    const int g = blockIdx.x;
    const int xcd = g & 7;
    const int b = xcd >> 1;                       // batch -> XCD pair
    const int nb = ((g >> 3) << 1) | (xcd & 1);   // q-block within batch

    const int tid = threadIdx.x;
    const int w = tid >> 6, l = tid & 63;
    const int lr = l & 15, lg = l >> 4;
    const int fn = w >> 1, fmb = (w & 1) * 2;     // S-phase role
    const int cb = w * 64;                        // PV role: channel base

    if (tid < 64) den_lds[tid] = 0.f;

    // hoisted Q A-fragments
    f16x8 Aq0, Aq1;
    {
        const u16* qp = Qh + ((size_t)b * NTOK + nb * 64 + fn * 16 + lr) * OQK + lg * 8;
        Aq0 = *reinterpret_cast<const f16x8*>(qp);
        Aq1 = *reinterpret_cast<const f16x8*>(qp + 32);
    }

    f32x4 acc[4][4] = {};                         // [row-frag a][chan-frag cf]
    float den[4] = {0.f, 0.f, 0.f, 0.f};
    const u16* Kbase = Kh + (size_t)b * NTOK * OQK;
    const u16* Vbase = Vb + (size_t)b * CIN * NTOK;

    // static-indexed double buffers (registers, never scratch)
    f16x8 KfA[2][2], KfB[2][2];
    s16x8 VcA[4][2], VcB[4][2];

    // prologue: tile0 S-phase -> Pt[0]; V(0) in VcA; K(1) in KfB
    LOADK(0, KfA);
    LOADV(0, VcA);
    SPHASE(KfA, 0);
    LOADK(1, KfB);

    for (int mt2 = 0; mt2 < 64; mt2 += 2) {
        BODY(0, VcA, VcB, KfB, KfA, mt2);
        BODY(1, VcB, VcA, KfA, KfB, mt2 + 1);
    }

    // ---- denominator reduce ----
    #pragma unroll
    for (int r = 0; r < 4; ++r) {
        float d = den[r];
        d += __shfl_xor(d, 1);
        d += __shfl_xor(d, 2);
        d += __shfl_xor(d, 4);
        d += __shfl_xor(d, 8);
        den[r] = d;
    }
    if (lr == 0) {
        #pragma unroll
        for (int r = 0; r < 4; ++r)
            atomicAdd(&den_lds[fn * 16 + lg * 4 + r], den[r]);
    }
    __syncthreads();

    // ---- epilogue: out = x_t + acc/den ----
    float inv[4][4];
    #pragma unroll
    for (int a = 0; a < 4; ++a) {
        #pragma unroll
        for (int r = 0; r < 4; ++r)
            inv[a][r] = 1.0f / den_lds[a * 16 + lg * 4 + r];
    }
    const float* xtp = x + (size_t)(b + NBATCH) * CIN * NTOK;
    float* op = out + (size_t)(b + NBATCH) * CIN * NTOK;
    #pragma unroll
    for (int a = 0; a < 4; ++a) {
        #pragma unroll
        for (int cf = 0; cf < 4; ++cf) {
            const int c = cb + cf * 16 + lr;
            const size_t base = (size_t)c * NTOK + nb * 64 + a * 16 + lg * 4;
            f32x4 xv = *reinterpret_cast<const f32x4*>(xtp + base);
            f32x4 o;
            #pragma unroll
            for (int r = 0; r < 4; ++r) o[r] = xv[r] + acc[a][cf][r] * inv[a][r];
            *reinterpret_cast<f32x4*>(op + base) = o;
        }
    }
}

extern "C" void kernel_launch(void* const* d_in, const int* in_sizes, int n_in,
                              void* d_out, int out_size, void* d_ws, size_t ws_size,
                              hipStream_t stream)
{
    (void)in_sizes; (void)n_in; (void)out_size; (void)ws_size;
    const float* x  = (const float*)d_in[0];
    const float* Wq = (const float*)d_in[1];
    const float* bq = (const float*)d_in[2];
    const float* Wk = (const float*)d_in[3];
    const float* bk = (const float*)d_in[4];
    const float* Wv = (const float*)d_in[5];
    const float* bv = (const float*)d_in[6];
    float* out = (float*)d_out;

    u16* Qh = (u16*)d_ws;                                   // 4*4096*64 f16
    u16* Kh = Qh + (size_t)NBATCH * NTOK * OQK;             // 4*4096*64 f16
    u16* Vb = Kh + (size_t)NBATCH * NTOK * OQK;             // 4*512*4096 bf16

    proj_qk<<<dim3(128, NBATCH), 256, 0, stream>>>(x, Wq, bq, Wk, bk, Qh, Kh, out);
    proj_v <<<dim3(128, NBATCH), 256, 0, stream>>>(x, Wv, bv, Vb);
    attn   <<<256, 512, 0, stream>>>(x, Qh, Kh, Vb, out);
}